// Round 3
// baseline (383.996 us; speedup 1.0000x reference)
//
#include <hip/hip_runtime.h>

// VectorQuantizer on MI355X — replicate numpy-fp32 rounding in the distance,
// so argmin matches the np reference's grid-quantized distances exactly.
// x: (32,256,32,32) fp32, codebook: (1024,256) fp32.
// Outputs concat: quantized (8388608 f32), vq_loss (1 f32), indices (32768 as f32).

#define NUM_K 1024
#define DIM   256
#define HW    1024          // H*W
#define N_TOT 32768         // B*H*W
#define TM    64            // n-tile per block
#define TK    64            // k-tile
#define DB    32            // d-chunk staged per inner pass
#define LOSS_OFF 8388608
#define IDX_OFF  8388609

// numpy pairwise sum of squares over 256 elements, exact numpy order:
// n=256 -> pairwise(a,128) + pairwise(a+128,128); each 128-block uses 8
// accumulators r[j] += a[i+j] (i=8..120 step 8), combined as
// ((r0+r1)+(r2+r3))+((r4+r5)+(r6+r7)). a[d] = fl32(v*v).
// __fmul_rn/__fadd_rn prevent FMA contraction from changing the rounding.
__device__ __forceinline__ float np_sumsq_256(const float* p, int stride) {
    float s[2];
    #pragma unroll
    for (int h = 0; h < 2; ++h) {
        const float* base = p + h * 128 * stride;
        float r[8];
        #pragma unroll
        for (int j = 0; j < 8; ++j) {
            float v = base[j * stride];
            r[j] = __fmul_rn(v, v);
        }
        for (int i = 8; i < 128; i += 8) {
            #pragma unroll
            for (int j = 0; j < 8; ++j) {
                float v = base[(i + j) * stride];
                r[j] = __fadd_rn(r[j], __fmul_rn(v, v));
            }
        }
        s[h] = __fadd_rn(__fadd_rn(__fadd_rn(r[0], r[1]), __fadd_rn(r[2], r[3])),
                         __fadd_rn(__fadd_rn(r[4], r[5]), __fadd_rn(r[6], r[7])));
    }
    return __fadd_rn(s[0], s[1]);
}

__global__ __launch_bounds__(256) void u2_kernel(const float* __restrict__ cb,
                                                 float* __restrict__ u2) {
    int k = blockIdx.x * 256 + threadIdx.x;     // 4 blocks x 256
    u2[k] = np_sumsq_256(cb + (size_t)k * DIM, 1);
}

__global__ __launch_bounds__(256, 2) void vq_main(const float* __restrict__ x,
                                                  const float* __restrict__ cb,
                                                  const float* __restrict__ u2,
                                                  float* __restrict__ out) {
    __shared__ float zT[DIM][TM];      // 64 KB  zT[d][m]
    __shared__ float eT[DB][TK];       // 8 KB   eT[d][k]
    __shared__ float Ts[TM];           // 256 B  numpy-order ||z||^2 per row
    __shared__ float red_v[4][TM];     // 1 KB
    __shared__ int   red_k[4][TM];     // 1 KB
    __shared__ int   bestk_s[TM];      // 256 B
    __shared__ float wsum[4];

    const int t  = threadIdx.x;
    const int g  = blockIdx.x;          // 512 blocks
    const int n0 = g * TM;
    const int b  = n0 >> 10;            // /1024
    const int r0 = n0 & (HW - 1);
    const size_t xbase = (size_t)b * (DIM * HW) + r0;

    // ---- stage zT[d][m] = x_flat[xbase + d*1024 + m] (coalesced float4) ----
    {
        const int f4 = (t & 15) * 4;
        const int dr = t >> 4;
        #pragma unroll
        for (int it = 0; it < 16; ++it) {
            int d = it * 16 + dr;
            float4 v = *(const float4*)(x + xbase + (size_t)d * HW + f4);
            *(float4*)&zT[d][f4] = v;
        }
    }
    __syncthreads();

    // ---- numpy-order ||z||^2 per row (one thread per row; visible to all
    // after the dc-loop's first __syncthreads, used only at tile epilogues) ----
    if (t < TM) Ts[t] = np_sumsq_256(&zT[0][t], TM);

    const int tm4 = (t & 15) * 4;       // 4 m's per thread
    const int tk4 = (t >> 4) * 4;       // 4 k's (within k-tile) per thread

    float best_v[4] = {3.4e38f, 3.4e38f, 3.4e38f, 3.4e38f};
    int   best_k[4] = {0, 0, 0, 0};

    for (int kt = 0; kt < NUM_K / TK; ++kt) {
        const int k0 = kt * TK;
        double accd[4][4];
        #pragma unroll
        for (int i = 0; i < 4; ++i)
            #pragma unroll
            for (int j = 0; j < 4; ++j) accd[i][j] = 0.0;

        for (int dc = 0; dc < DIM / DB; ++dc) {
            const int d0 = dc * DB;
            // stage eT[d][k] = cb[k0+k][d0+d]
            {
                const int kk = t >> 2;            // 0..63
                const int dd = (t & 3) * 8;       // 0,8,16,24
                const float* src = cb + (size_t)(k0 + kk) * DIM + d0 + dd;
                float4 a  = *(const float4*)src;
                float4 c4 = *(const float4*)(src + 4);
                eT[dd + 0][kk] = a.x;  eT[dd + 1][kk] = a.y;
                eT[dd + 2][kk] = a.z;  eT[dd + 3][kk] = a.w;
                eT[dd + 4][kk] = c4.x; eT[dd + 5][kk] = c4.y;
                eT[dd + 6][kk] = c4.z; eT[dd + 7][kk] = c4.w;
            }
            __syncthreads();

            float af[4][4];
            #pragma unroll
            for (int i = 0; i < 4; ++i)
                #pragma unroll
                for (int j = 0; j < 4; ++j) af[i][j] = 0.f;

            #pragma unroll 8
            for (int d = 0; d < DB; ++d) {
                float4 zv = *(const float4*)&zT[d0 + d][tm4];
                float4 ev = *(const float4*)&eT[d][tk4];
                af[0][0] = fmaf(zv.x, ev.x, af[0][0]);
                af[0][1] = fmaf(zv.x, ev.y, af[0][1]);
                af[0][2] = fmaf(zv.x, ev.z, af[0][2]);
                af[0][3] = fmaf(zv.x, ev.w, af[0][3]);
                af[1][0] = fmaf(zv.y, ev.x, af[1][0]);
                af[1][1] = fmaf(zv.y, ev.y, af[1][1]);
                af[1][2] = fmaf(zv.y, ev.z, af[1][2]);
                af[1][3] = fmaf(zv.y, ev.w, af[1][3]);
                af[2][0] = fmaf(zv.z, ev.x, af[2][0]);
                af[2][1] = fmaf(zv.z, ev.y, af[2][1]);
                af[2][2] = fmaf(zv.z, ev.z, af[2][2]);
                af[2][3] = fmaf(zv.z, ev.w, af[2][3]);
                af[3][0] = fmaf(zv.w, ev.x, af[3][0]);
                af[3][1] = fmaf(zv.w, ev.y, af[3][1]);
                af[3][2] = fmaf(zv.w, ev.z, af[3][2]);
                af[3][3] = fmaf(zv.w, ev.w, af[3][3]);
            }
            #pragma unroll
            for (int i = 0; i < 4; ++i)
                #pragma unroll
                for (int j = 0; j < 4; ++j) accd[i][j] += (double)af[i][j];
            __syncthreads();
        }

        // ---- replicate numpy: d = fl32( fl32(T_n + U_k) - 2*fl32(dot) ) ----
        float4 uv = *(const float4*)(u2 + k0 + tk4);
        float ua[4] = {uv.x, uv.y, uv.z, uv.w};
        #pragma unroll
        for (int j = 0; j < 4; ++j) {
            const int kk = k0 + tk4 + j;
            #pragma unroll
            for (int i = 0; i < 4; ++i) {
                float m32 = (float)accd[i][j];              // fl32(dot)
                float c   = __fmul_rn(2.0f, m32);           // exact
                float t1  = __fadd_rn(Ts[tm4 + i], ua[j]);  // fl32(T+U)
                float d32 = __fsub_rn(t1, c);               // fl32(t1-c)
                // strict < keeps the earliest k (ks ascend within a thread)
                if (d32 < best_v[i]) { best_v[i] = d32; best_k[i] = kk; }
            }
        }
    }

    // ---- argmin reduction across the 4 tk-subgroups within the wave ----
    #pragma unroll
    for (int i = 0; i < 4; ++i) {
        float v = best_v[i]; int k = best_k[i];
        #pragma unroll
        for (int off = 16; off < 64; off <<= 1) {
            float ov = __shfl_xor(v, off, 64);
            int   ok = __shfl_xor(k, off, 64);
            if (ov < v || (ov == v && ok < k)) { v = ov; k = ok; }
        }
        best_v[i] = v; best_k[i] = k;
    }
    const int wv = t >> 6;              // wave id 0..3
    if ((t & 63) < 16) {
        #pragma unroll
        for (int i = 0; i < 4; ++i) {
            red_v[wv][tm4 + i] = best_v[i];
            red_k[wv][tm4 + i] = best_k[i];
        }
    }
    __syncthreads();
    if (t < TM) {
        float bv = red_v[0][t]; int bk = red_k[0][t];
        #pragma unroll
        for (int q = 1; q < 4; ++q) {
            float v = red_v[q][t]; int k = red_k[q][t];
            if (v < bv || (v == bv && k < bk)) { bv = v; bk = k; }
        }
        bestk_s[t] = bk;
        out[IDX_OFF + n0 + t] = (float)bk;   // indices as float
    }
    __syncthreads();

    // ---- epilogue: quantized output + fused loss ----
    float lsum = 0.f;
    {
        const int m = t & 63;
        const int kq = bestk_s[m];
        const float* crow = cb + (size_t)kq * DIM;
        for (int c = (t >> 6); c < DIM; c += 4) {
            float qv = crow[c];
            float xv = zT[c][m];
            float d  = qv - xv;
            lsum = fmaf(d, d, lsum);
            out[xbase + (size_t)c * HW + m] = qv;
        }
    }
    #pragma unroll
    for (int off = 32; off > 0; off >>= 1) lsum += __shfl_down(lsum, off, 64);
    if ((t & 63) == 0) wsum[wv] = lsum;
    __syncthreads();
    if (t == 0) {
        float s = (wsum[0] + wsum[1]) + (wsum[2] + wsum[3]);
        // vq_loss = q_latent + 0.25*e_latent, both equal mean((q-x)^2)
        atomicAdd(out + LOSS_OFF, s * (1.25f / 8388608.0f));
    }
}

extern "C" void kernel_launch(void* const* d_in, const int* in_sizes, int n_in,
                              void* d_out, int out_size, void* d_ws, size_t ws_size,
                              hipStream_t stream) {
    const float* x  = (const float*)d_in[0];
    const float* cb = (const float*)d_in[1];
    float* out = (float*)d_out;
    float* u2  = (float*)d_ws;          // 4 KB scratch (numpy-order ||e||^2)

    // zero the loss slot (atomicAdd target); graph-capture-safe
    hipMemsetAsync(out + LOSS_OFF, 0, sizeof(float), stream);
    u2_kernel<<<NUM_K / 256, 256, 0, stream>>>(cb, u2);
    vq_main<<<N_TOT / TM, 256, 0, stream>>>(x, cb, u2, out);
}